// Round 1
// baseline (3380.844 us; speedup 1.0000x reference)
//
#include <hip/hip_runtime.h>
#include <math.h>

// Problem constants
#define BATCH 4
#define CH 512
#define NTOK 4096       // 64*64
#define NGRP 32
#define CPG 16          // channels per group
#define GN_EPS 1e-6f

#define BM 64
#define BN 64
#define BK 16

// ---------------------------------------------------------------------------
// GroupNorm: one block per (batch, group). 16 channels x 4096 spatial each.
// ---------------------------------------------------------------------------
__global__ __launch_bounds__(256)
void groupnorm_kernel(const float* __restrict__ x,
                      const float* __restrict__ gamma,
                      const float* __restrict__ beta,
                      float* __restrict__ hn)
{
    const int bg = blockIdx.x;
    const int b = bg / NGRP;
    const int g = bg % NGRP;
    const float* xp = x + ((size_t)b * CH + (size_t)g * CPG) * NTOK;
    float* hp = hn + ((size_t)b * CH + (size_t)g * CPG) * NTOK;
    const int total = CPG * NTOK;  // 65536

    float s = 0.f, ss = 0.f;
    for (int idx = threadIdx.x; idx < total; idx += 256) {
        float v = xp[idx];
        s += v;
        ss += v * v;
    }
    __shared__ float red0[4], red1[4];
    for (int off = 32; off >= 1; off >>= 1) {
        s  += __shfl_down(s, off);
        ss += __shfl_down(ss, off);
    }
    const int lane = threadIdx.x & 63;
    const int wave = threadIdx.x >> 6;
    if (lane == 0) { red0[wave] = s; red1[wave] = ss; }
    __syncthreads();
    if (threadIdx.x == 0) {
        float ts = 0.f, tss = 0.f;
        for (int i = 0; i < 4; i++) { ts += red0[i]; tss += red1[i]; }
        red0[0] = ts;
        red1[0] = tss;
    }
    __syncthreads();
    const float mean = red0[0] / (float)total;
    const float var = red1[0] / (float)total - mean * mean;
    const float rstd = rsqrtf(var + GN_EPS);

    for (int idx = threadIdx.x; idx < total; idx += 256) {
        const int cglob = g * CPG + idx / NTOK;
        const float vn = (xp[idx] - mean) * rstd;
        hp[idx] = vn * gamma[cglob] + beta[cglob];
    }
}

// ---------------------------------------------------------------------------
// Generic fp32 tiled GEMM: C[m][n] = scale * sum_k Aval(m,k)*Bval(k,n) + bias
//   Aval(m,k) = TA ? A[k*M + m] : A[m*K + k]
//   Bval(k,n) = TB ? B[n*K + k] : B[k*N + n]
// All dims assumed multiples of tile sizes (true here: 512/4096).
// ---------------------------------------------------------------------------
template<bool TA, bool TB, bool ADD_RES>
__global__ __launch_bounds__(256)
void gemm_kernel(const float* __restrict__ A,
                 const float* __restrict__ Bmat,
                 float* __restrict__ Cmat,
                 const float* __restrict__ bias,   // per-row [M], may be null
                 const float* __restrict__ res,    // residual, same layout as C
                 float scale,
                 int M, int N, int K,
                 long strideA, long strideB, long strideC)
{
    __shared__ float As[BK][BM + 1];
    __shared__ float Bs[BK][BN + 1];

    const int z = blockIdx.z;
    const float* Ap = A + (size_t)z * strideA;
    const float* Bp = Bmat + (size_t)z * strideB;
    float* Cp = Cmat + (size_t)z * strideC;
    const float* Rp = res + (size_t)z * strideC;

    const int n0 = blockIdx.x * BN;
    const int m0 = blockIdx.y * BM;
    const int t = threadIdx.x;
    const int tn = t & 15;
    const int tm = t >> 4;

    const int lda = TA ? M : K;
    const int ldb = TB ? K : N;

    float acc[4][4];
#pragma unroll
    for (int i = 0; i < 4; i++)
#pragma unroll
        for (int j = 0; j < 4; j++) acc[i][j] = 0.f;

    for (int k0 = 0; k0 < K; k0 += BK) {
        if (TA) {
            const int kk = t >> 4;
            const int mq = (t & 15) << 2;
            const float4 va = *(const float4*)(Ap + (size_t)(k0 + kk) * lda + m0 + mq);
            As[kk][mq + 0] = va.x; As[kk][mq + 1] = va.y;
            As[kk][mq + 2] = va.z; As[kk][mq + 3] = va.w;
        } else {
            const int mm = t >> 2;
            const int kq = (t & 3) << 2;
            const float4 va = *(const float4*)(Ap + (size_t)(m0 + mm) * lda + k0 + kq);
            As[kq + 0][mm] = va.x; As[kq + 1][mm] = va.y;
            As[kq + 2][mm] = va.z; As[kq + 3][mm] = va.w;
        }
        if (TB) {
            const int nn = t >> 2;
            const int kq = (t & 3) << 2;
            const float4 vb = *(const float4*)(Bp + (size_t)(n0 + nn) * ldb + k0 + kq);
            Bs[kq + 0][nn] = vb.x; Bs[kq + 1][nn] = vb.y;
            Bs[kq + 2][nn] = vb.z; Bs[kq + 3][nn] = vb.w;
        } else {
            const int kk = t >> 4;
            const int nq = (t & 15) << 2;
            const float4 vb = *(const float4*)(Bp + (size_t)(k0 + kk) * ldb + n0 + nq);
            Bs[kk][nq + 0] = vb.x; Bs[kk][nq + 1] = vb.y;
            Bs[kk][nq + 2] = vb.z; Bs[kk][nq + 3] = vb.w;
        }
        __syncthreads();
#pragma unroll
        for (int kk = 0; kk < BK; kk++) {
            float a[4], b[4];
#pragma unroll
            for (int i = 0; i < 4; i++) a[i] = As[kk][tm * 4 + i];
#pragma unroll
            for (int j = 0; j < 4; j++) b[j] = Bs[kk][tn + 16 * j];
#pragma unroll
            for (int i = 0; i < 4; i++)
#pragma unroll
                for (int j = 0; j < 4; j++)
                    acc[i][j] += a[i] * b[j];
        }
        __syncthreads();
    }

#pragma unroll
    for (int i = 0; i < 4; i++) {
        const int row = m0 + tm * 4 + i;
        const float bv = bias ? bias[row] : 0.f;
#pragma unroll
        for (int j = 0; j < 4; j++) {
            const int col = n0 + tn + 16 * j;
            const size_t idx = (size_t)row * N + col;
            float v = acc[i][j] * scale + bv;
            if (ADD_RES) v += Rp[idx];
            Cp[idx] = v;
        }
    }
}

// ---------------------------------------------------------------------------
// Row softmax, in place. One block per row of [NROWS x N].
// ---------------------------------------------------------------------------
__global__ __launch_bounds__(256)
void softmax_kernel(float* __restrict__ s, int N)
{
    float* row = s + (size_t)blockIdx.x * N;
    __shared__ float red[4];
    const int t = threadIdx.x;
    const int lane = t & 63;
    const int wave = t >> 6;

    float m = -1e30f;
    for (int j = t; j < N; j += 256) m = fmaxf(m, row[j]);
    for (int off = 32; off >= 1; off >>= 1) m = fmaxf(m, __shfl_down(m, off));
    if (lane == 0) red[wave] = m;
    __syncthreads();
    if (t == 0) {
        float mm = red[0];
        for (int i = 1; i < 4; i++) mm = fmaxf(mm, red[i]);
        red[0] = mm;
    }
    __syncthreads();
    m = red[0];
    __syncthreads();   // everyone has read red[0] before reuse

    float sum = 0.f;
    for (int j = t; j < N; j += 256) sum += __expf(row[j] - m);
    for (int off = 32; off >= 1; off >>= 1) sum += __shfl_down(sum, off);
    if (lane == 0) red[wave] = sum;
    __syncthreads();
    if (t == 0) red[0] = 1.f / (red[0] + red[1] + red[2] + red[3]);
    __syncthreads();
    const float inv = red[0];

    for (int j = t; j < N; j += 256) row[j] = __expf(row[j] - m) * inv;
}

// ---------------------------------------------------------------------------
// Launch
// ---------------------------------------------------------------------------
extern "C" void kernel_launch(void* const* d_in, const int* in_sizes, int n_in,
                              void* d_out, int out_size, void* d_ws, size_t ws_size,
                              hipStream_t stream)
{
    const float* x      = (const float*)d_in[0];
    const float* norm_w = (const float*)d_in[1];
    const float* norm_b = (const float*)d_in[2];
    const float* q_w    = (const float*)d_in[3];
    const float* q_b    = (const float*)d_in[4];
    const float* k_w    = (const float*)d_in[5];
    const float* k_b    = (const float*)d_in[6];
    const float* v_w    = (const float*)d_in[7];
    const float* v_b    = (const float*)d_in[8];
    const float* p_w    = (const float*)d_in[9];
    const float* p_b    = (const float*)d_in[10];
    float* out = (float*)d_out;

    const size_t CN  = (size_t)CH * NTOK;          // per-batch plane, 2M floats
    const size_t BCN = (size_t)BATCH * CN;         // 8.4M floats

    float* hn = (float*)d_ws;        // [B][C][N]
    float* q  = hn + BCN;            // [B][C][N]
    float* k  = q + BCN;
    float* v  = k + BCN;
    float* o  = v + BCN;             // attention output [B][C][N]
    float* s  = o + BCN;             // scores, single batch [N][N]

    // 1. GroupNorm
    groupnorm_kernel<<<BATCH * NGRP, 256, 0, stream>>>(x, norm_w, norm_b, hn);

    // 2. Q/K/V 1x1 convs: NN GEMM, batched over z
    dim3 gconv(NTOK / BN, CH / BM, BATCH);
    gemm_kernel<false, false, false><<<gconv, 256, 0, stream>>>(
        q_w, hn, q, q_b, nullptr, 1.f, CH, NTOK, CH, 0, (long)CN, (long)CN);
    gemm_kernel<false, false, false><<<gconv, 256, 0, stream>>>(
        k_w, hn, k, k_b, nullptr, 1.f, CH, NTOK, CH, 0, (long)CN, (long)CN);
    gemm_kernel<false, false, false><<<gconv, 256, 0, stream>>>(
        v_w, hn, v, v_b, nullptr, 1.f, CH, NTOK, CH, 0, (long)CN, (long)CN);

    // 3. Attention, batch-sequential to keep scores buffer at one batch
    const float scale = 1.0f / sqrtf((float)CH);
    for (int b = 0; b < BATCH; b++) {
        // scores[i][j] = scale * sum_c q[c][i] * k[c][j]   (TN)
        dim3 gs(NTOK / BN, NTOK / BM, 1);
        gemm_kernel<true, false, false><<<gs, 256, 0, stream>>>(
            q + b * CN, k + b * CN, s, nullptr, nullptr, scale,
            NTOK, NTOK, CH, 0, 0, 0);
        // softmax over j
        softmax_kernel<<<NTOK, 256, 0, stream>>>(s, NTOK);
        // o[c][i] = sum_j v[c][j] * p[i][j]   (NT)
        dim3 gp(NTOK / BN, CH / BM, 1);
        gemm_kernel<false, true, false><<<gp, 256, 0, stream>>>(
            v + b * CN, s, o + b * CN, nullptr, nullptr, 1.f,
            CH, NTOK, NTOK, 0, 0, 0);
    }

    // 4. Proj + bias + residual -> out
    gemm_kernel<false, false, true><<<gconv, 256, 0, stream>>>(
        p_w, o, out, p_b, x, 1.f, CH, NTOK, CH, 0, (long)CN, (long)CN);
}

// Round 2
// 679.428 us; speedup vs baseline: 4.9760x; 4.9760x over previous
//
#include <hip/hip_runtime.h>
#include <math.h>

#define BATCH 4
#define CH 512
#define NTOK 4096
#define NGRP 32
#define CPG 16
#define GN_EPS 1e-6f

typedef __attribute__((ext_vector_type(8))) short short8;
typedef __attribute__((ext_vector_type(4))) short short4v;
typedef __attribute__((ext_vector_type(4))) float floatx4;

__device__ __forceinline__ short f2bf(float f) {
    unsigned u = __float_as_uint(f);
    u += 0x7fffu + ((u >> 16) & 1u);
    return (short)(u >> 16);
}

__device__ __forceinline__ void load_lds16(const void* g, void* l) {
    __builtin_amdgcn_global_load_lds(
        (const __attribute__((address_space(1))) void*)g,
        (__attribute__((address_space(3))) void*)l,
        16, 0, 0);
}

// ---------------------------------------------------------------------------
// GroupNorm pass 1: per (b,g) mean/rstd. 128 blocks.
// ---------------------------------------------------------------------------
__global__ __launch_bounds__(256)
void gn_stats(const float* __restrict__ x, float2* __restrict__ stat)
{
    const int bg = blockIdx.x;
    const float4* xp = (const float4*)(x + (size_t)bg * CPG * NTOK);
    float s = 0.f, ss = 0.f;
    for (int i = threadIdx.x; i < CPG * NTOK / 4; i += 256) {
        float4 v = xp[i];
        s  += v.x + v.y + v.z + v.w;
        ss += v.x * v.x + v.y * v.y + v.z * v.z + v.w * v.w;
    }
    __shared__ float r0[4], r1[4];
    for (int off = 32; off >= 1; off >>= 1) {
        s  += __shfl_down(s, off);
        ss += __shfl_down(ss, off);
    }
    const int lane = threadIdx.x & 63, wave = threadIdx.x >> 6;
    if (lane == 0) { r0[wave] = s; r1[wave] = ss; }
    __syncthreads();
    if (threadIdx.x == 0) {
        float ts = r0[0] + r0[1] + r0[2] + r0[3];
        float tss = r1[0] + r1[1] + r1[2] + r1[3];
        const float inv = 1.f / (float)(CPG * NTOK);
        float mean = ts * inv;
        float var = tss * inv - mean * mean;
        float2 o; o.x = mean; o.y = rsqrtf(var + GN_EPS);
        stat[bg] = o;
    }
}

// ---------------------------------------------------------------------------
// GroupNorm pass 2: normalize + affine + transpose + bf16 cast.
// x[b][c][n] fp32 -> hnT[b][n][c] bf16.  Grid (NTOK/32, CH/32, BATCH).
// ---------------------------------------------------------------------------
__global__ __launch_bounds__(256)
void gn_apply_t(const float* __restrict__ x, const float* __restrict__ gamma,
                const float* __restrict__ beta, const float2* __restrict__ stat,
                short* __restrict__ hnT)
{
    const int b = blockIdx.z;
    const int c0 = blockIdx.y * 32;
    const int n0 = blockIdx.x * 32;
    __shared__ short tile[32][33];
    const int t = threadIdx.x;

    const int cl = t >> 3;          // 0..31
    const int nl = (t & 7) * 4;     // 0..28
    const int c = c0 + cl;
    const float2 st = stat[b * NGRP + c / CPG];
    const float ga = gamma[c], be = beta[c];
    const float4 v = *(const float4*)(x + ((size_t)b * CH + c) * NTOK + n0 + nl);
    tile[cl][nl + 0] = f2bf((v.x - st.x) * st.y * ga + be);
    tile[cl][nl + 1] = f2bf((v.y - st.x) * st.y * ga + be);
    tile[cl][nl + 2] = f2bf((v.z - st.x) * st.y * ga + be);
    tile[cl][nl + 3] = f2bf((v.w - st.x) * st.y * ga + be);
    __syncthreads();

    const int nw = t >> 3;          // 0..31
    const int cw = (t & 7) * 4;     // 0..28
    short4v o;
    o.x = tile[cw + 0][nw];
    o.y = tile[cw + 1][nw];
    o.z = tile[cw + 2][nw];
    o.w = tile[cw + 3][nw];
    *(short4v*)(hnT + ((size_t)b * NTOK + n0 + nw) * CH + c0 + cw) = o;
}

// ---------------------------------------------------------------------------
// fp32 -> bf16 weight cast. Grid (256, 4).
// ---------------------------------------------------------------------------
__global__ __launch_bounds__(256)
void cast_weights(const float* w0, const float* w1, const float* w2, const float* w3,
                  short* o0, short* o1, short* o2, short* o3)
{
    const float* w; short* o;
    switch (blockIdx.y) {
        case 0: w = w0; o = o0; break;
        case 1: w = w1; o = o1; break;
        case 2: w = w2; o = o2; break;
        default: w = w3; o = o3; break;
    }
    const int i = blockIdx.x * 256 + threadIdx.x;   // float4 index; 512*512/4 = 65536 total
    const float4 v = ((const float4*)w)[i];
    short4v s; s.x = f2bf(v.x); s.y = f2bf(v.y); s.z = f2bf(v.z); s.w = f2bf(v.w);
    ((short4v*)o)[i] = s;
}

// ---------------------------------------------------------------------------
// bf16 MFMA GEMM (TN): C[m][n] = scale*sum_k A[m][k]*B[n][k] (+bias)(+res)
// BM=128 fixed, BK=32. 256 threads = 4 waves.
// ---------------------------------------------------------------------------
template<int BN, int WAVES_M, int OUT_BF16, int BIAS_M, int BIAS_N, int ADD_RES>
__global__ __launch_bounds__(256)
void mfma_gemm(const short* __restrict__ A, const short* __restrict__ B,
               void* __restrict__ Cv, const float* __restrict__ bias,
               const float* __restrict__ res, float scale,
               int K, int lda, int ldb, int ldc,
               long sA, long sB, long sC)
{
    constexpr int WAVES_N = 4 / WAVES_M;
    constexpr int WM = 128 / WAVES_M;
    constexpr int WN = BN / WAVES_N;
    constexpr int MT = WM / 16;
    constexpr int NT = WN / 16;

    __shared__ __align__(16) short As[128 * 32];
    __shared__ __align__(16) short Bs[BN * 32];

    const int z = blockIdx.z;
    const short* Ap = A + (size_t)z * sA;
    const short* Bp = B + (size_t)z * sB;

    const int m0 = blockIdx.y * 128;
    const int n0 = blockIdx.x * BN;
    const int t = threadIdx.x;
    const int w = t >> 6, lane = t & 63;
    const int wm = (w % WAVES_M) * WM;
    const int wn = (w / WAVES_M) * WN;
    const int lr = lane & 15, lq = lane >> 4;

    floatx4 acc[MT][NT];
#pragma unroll
    for (int mt = 0; mt < MT; mt++)
#pragma unroll
        for (int nt = 0; nt < NT; nt++)
            acc[mt][nt] = (floatx4){0.f, 0.f, 0.f, 0.f};

    const int rA = t >> 2;          // 0..63 (row within tile)
    const int kA = (t & 3) * 8;     // 0,8,16,24

    for (int k0 = 0; k0 < K; k0 += 32) {
        // stage A: 128x32 bf16 = 8KB -> 2 issues of 16B/thread
        const short* a0 = Ap + (size_t)(m0 + rA) * lda + k0 + kA;
        load_lds16(a0, &As[rA * 32 + kA]);
        load_lds16(a0 + (size_t)64 * lda, &As[(rA + 64) * 32 + kA]);
        // stage B
        const short* b0 = Bp + (size_t)(n0 + rA) * ldb + k0 + kA;
        load_lds16(b0, &Bs[rA * 32 + kA]);
        if (BN == 128)
            load_lds16(b0 + (size_t)64 * ldb, &Bs[(rA + 64) * 32 + kA]);
        __syncthreads();

        short8 af[MT], bfr[NT];
#pragma unroll
        for (int mt = 0; mt < MT; mt++)
            af[mt] = *(const short8*)&As[(wm + mt * 16 + lr) * 32 + lq * 8];
#pragma unroll
        for (int nt = 0; nt < NT; nt++)
            bfr[nt] = *(const short8*)&Bs[(wn + nt * 16 + lr) * 32 + lq * 8];
#pragma unroll
        for (int mt = 0; mt < MT; mt++)
#pragma unroll
            for (int nt = 0; nt < NT; nt++)
                acc[mt][nt] = __builtin_amdgcn_mfma_f32_16x16x32_bf16(
                    af[mt], bfr[nt], acc[mt][nt], 0, 0, 0);
        __syncthreads();
    }

    // Epilogue. C/D: col = lane&15, row = (lane>>4)*4 + r  [m89-verified]
    const size_t cz = (size_t)z * sC;
#pragma unroll
    for (int mt = 0; mt < MT; mt++) {
#pragma unroll
        for (int nt = 0; nt < NT; nt++) {
#pragma unroll
            for (int r = 0; r < 4; r++) {
                const int row = m0 + wm + mt * 16 + lq * 4 + r;
                const int col = n0 + wn + nt * 16 + lr;
                float v = acc[mt][nt][r] * scale;
                if (BIAS_M) v += bias[row];
                if (BIAS_N) v += bias[col];
                const size_t idx = cz + (size_t)row * ldc + col;
                if (ADD_RES) v += res[idx];
                if (OUT_BF16) ((short*)Cv)[idx] = f2bf(v);
                else          ((float*)Cv)[idx] = v;
            }
        }
    }
}

// ---------------------------------------------------------------------------
// Row softmax fp32 -> bf16 P, overlaid in place (P row pitch 8192 bf16).
// ---------------------------------------------------------------------------
__global__ __launch_bounds__(256)
void softmax_rows(float* __restrict__ S)
{
    float* row = S + (size_t)blockIdx.x * NTOK;
    const int t = threadIdx.x;
    const int lane = t & 63, wave = t >> 6;
    __shared__ float redm[4], reds[4];

    float4 v[4];
#pragma unroll
    for (int j = 0; j < 4; j++) v[j] = ((const float4*)row)[t + 256 * j];

    float m = -1e30f;
#pragma unroll
    for (int j = 0; j < 4; j++)
        m = fmaxf(m, fmaxf(fmaxf(v[j].x, v[j].y), fmaxf(v[j].z, v[j].w)));
    for (int off = 32; off >= 1; off >>= 1) m = fmaxf(m, __shfl_down(m, off));
    if (lane == 0) redm[wave] = m;
    __syncthreads();
    m = fmaxf(fmaxf(redm[0], redm[1]), fmaxf(redm[2], redm[3]));

    float sum = 0.f;
#pragma unroll
    for (int j = 0; j < 4; j++) {
        v[j].x = __expf(v[j].x - m);
        v[j].y = __expf(v[j].y - m);
        v[j].z = __expf(v[j].z - m);
        v[j].w = __expf(v[j].w - m);
        sum += v[j].x + v[j].y + v[j].z + v[j].w;
    }
    for (int off = 32; off >= 1; off >>= 1) sum += __shfl_down(sum, off);
    if (lane == 0) reds[wave] = sum;
    __syncthreads();
    const float inv = 1.f / (reds[0] + reds[1] + reds[2] + reds[3]);

#pragma unroll
    for (int j = 0; j < 4; j++) {
        short4v o;
        o.x = f2bf(v[j].x * inv);
        o.y = f2bf(v[j].y * inv);
        o.z = f2bf(v[j].z * inv);
        o.w = f2bf(v[j].w * inv);
        ((short4v*)row)[t + 256 * j] = o;
    }
}

// ---------------------------------------------------------------------------
// Launch
// ---------------------------------------------------------------------------
extern "C" void kernel_launch(void* const* d_in, const int* in_sizes, int n_in,
                              void* d_out, int out_size, void* d_ws, size_t ws_size,
                              hipStream_t stream)
{
    (void)in_sizes; (void)n_in; (void)out_size; (void)ws_size;
    const float* x      = (const float*)d_in[0];
    const float* norm_w = (const float*)d_in[1];
    const float* norm_b = (const float*)d_in[2];
    const float* q_w    = (const float*)d_in[3];
    const float* q_b    = (const float*)d_in[4];
    const float* k_w    = (const float*)d_in[5];
    const float* k_b    = (const float*)d_in[6];
    const float* v_w    = (const float*)d_in[7];
    const float* v_b    = (const float*)d_in[8];
    const float* p_w    = (const float*)d_in[9];
    const float* p_b    = (const float*)d_in[10];

    const size_t CN2 = (size_t)NTOK * CH;   // 2,097,152 elements per batch plane

    short* hnT = (short*)d_ws;              // [B][N][C] bf16
    short* Q   = hnT + BATCH * CN2;         // [B][N][C]
    short* Kb  = Q   + BATCH * CN2;         // [B][N][C]
    short* V   = Kb  + BATCH * CN2;         // [B][C][N]
    short* O   = V   + BATCH * CN2;         // [B][N][C]
    short* wq  = O   + BATCH * CN2;
    short* wk  = wq + CH * CH;
    short* wv  = wk + CH * CH;
    short* wp  = wv + CH * CH;
    float2* stat = (float2*)(wp + CH * CH);               // 128 entries
    float* S = (float*)((char*)(stat + 128) + 0);         // [4096][4096] fp32, one batch

    // GroupNorm + transpose + casts
    gn_stats<<<BATCH * NGRP, 256, 0, stream>>>(x, stat);
    cast_weights<<<dim3(256, 4), 256, 0, stream>>>(q_w, k_w, v_w, p_w, wq, wk, wv, wp);
    gn_apply_t<<<dim3(NTOK / 32, CH / 32, BATCH), 256, 0, stream>>>(
        x, norm_w, norm_b, stat, hnT);

    // Q/K convs: C[token][c_out] bf16, bias per col
    mfma_gemm<128, 2, 1, 0, 1, 0><<<dim3(CH / 128, NTOK / 128, BATCH), 256, 0, stream>>>(
        hnT, wq, Q, q_b, nullptr, 1.f, CH, CH, CH, CH, (long)CN2, 0, (long)CN2);
    mfma_gemm<128, 2, 1, 0, 1, 0><<<dim3(CH / 128, NTOK / 128, BATCH), 256, 0, stream>>>(
        hnT, wk, Kb, k_b, nullptr, 1.f, CH, CH, CH, CH, (long)CN2, 0, (long)CN2);
    // V conv: C[c_out][token] bf16, bias per row
    mfma_gemm<128, 2, 1, 1, 0, 0><<<dim3(NTOK / 128, CH / 128, BATCH), 256, 0, stream>>>(
        wv, hnT, V, v_b, nullptr, 1.f, CH, CH, CH, NTOK, 0, (long)CN2, (long)CN2);

    const float scale = 1.0f / sqrtf((float)CH);
    for (int b = 0; b < BATCH; b++) {
        // scores: S[i][j] fp32
        mfma_gemm<128, 2, 0, 0, 0, 0><<<dim3(NTOK / 128, NTOK / 128, 1), 256, 0, stream>>>(
            Q + b * CN2, Kb + b * CN2, S, nullptr, nullptr, scale,
            CH, CH, CH, NTOK, 0, 0, 0);
        // softmax + bf16 pack (P pitch 8192 bf16, overlaid in S)
        softmax_rows<<<NTOK, 256, 0, stream>>>(S);
        // PV: O[i][c] bf16.  BN=64 -> 256 blocks.
        mfma_gemm<64, 4, 1, 0, 0, 0><<<dim3(CH / 64, NTOK / 128, 1), 256, 0, stream>>>(
            (const short*)S, V + b * CN2, O + b * CN2, nullptr, nullptr, 1.f,
            NTOK, 2 * NTOK, NTOK, CH, 0, 0, 0);
    }

    // proj + bias + residual -> out fp32 [b][c][n]
    mfma_gemm<128, 2, 0, 1, 0, 1><<<dim3(NTOK / 128, CH / 128, BATCH), 256, 0, stream>>>(
        wp, O, d_out, p_b, x, 1.f, CH, CH, CH, NTOK, 0, (long)CN2, (long)CN2);
}

// Round 3
// 509.320 us; speedup vs baseline: 6.6380x; 1.3340x over previous
//
#include <hip/hip_runtime.h>
#include <math.h>

#define BATCH 4
#define CH 512
#define NTOK 4096
#define NGRP 32
#define CPG 16
#define GN_EPS 1e-6f

typedef __attribute__((ext_vector_type(8))) short short8;
typedef __attribute__((ext_vector_type(4))) short short4v;
typedef __attribute__((ext_vector_type(4))) float floatx4;

__device__ __forceinline__ short f2bf(float f) {
    unsigned u = __float_as_uint(f);
    u += 0x7fffu + ((u >> 16) & 1u);
    return (short)(u >> 16);
}

__device__ __forceinline__ void load_lds16(const void* g, void* l) {
    __builtin_amdgcn_global_load_lds(
        (const __attribute__((address_space(1))) void*)g,
        (__attribute__((address_space(3))) void*)l,
        16, 0, 0);
}

// ---------------------------------------------------------------------------
// GroupNorm pass 1: per (b,g) mean/rstd. 128 blocks.
// ---------------------------------------------------------------------------
__global__ __launch_bounds__(256)
void gn_stats(const float* __restrict__ x, float2* __restrict__ stat)
{
    const int bg = blockIdx.x;
    const float4* xp = (const float4*)(x + (size_t)bg * CPG * NTOK);
    float s = 0.f, ss = 0.f;
    for (int i = threadIdx.x; i < CPG * NTOK / 4; i += 256) {
        float4 v = xp[i];
        s  += v.x + v.y + v.z + v.w;
        ss += v.x * v.x + v.y * v.y + v.z * v.z + v.w * v.w;
    }
    __shared__ float r0[4], r1[4];
    for (int off = 32; off >= 1; off >>= 1) {
        s  += __shfl_down(s, off);
        ss += __shfl_down(ss, off);
    }
    const int lane = threadIdx.x & 63, wave = threadIdx.x >> 6;
    if (lane == 0) { r0[wave] = s; r1[wave] = ss; }
    __syncthreads();
    if (threadIdx.x == 0) {
        float ts = r0[0] + r0[1] + r0[2] + r0[3];
        float tss = r1[0] + r1[1] + r1[2] + r1[3];
        const float inv = 1.f / (float)(CPG * NTOK);
        float mean = ts * inv;
        float var = tss * inv - mean * mean;
        float2 o; o.x = mean; o.y = rsqrtf(var + GN_EPS);
        stat[bg] = o;
    }
}

// ---------------------------------------------------------------------------
// GroupNorm pass 2: normalize + affine + transpose + bf16 cast.
// x[b][c][n] fp32 -> hnT[b][n][c] bf16.  Grid (NTOK/32, CH/32, BATCH).
// ---------------------------------------------------------------------------
__global__ __launch_bounds__(256)
void gn_apply_t(const float* __restrict__ x, const float* __restrict__ gamma,
                const float* __restrict__ beta, const float2* __restrict__ stat,
                short* __restrict__ hnT)
{
    const int b = blockIdx.z;
    const int c0 = blockIdx.y * 32;
    const int n0 = blockIdx.x * 32;
    __shared__ short tile[32][33];
    const int t = threadIdx.x;

    const int cl = t >> 3;          // 0..31
    const int nl = (t & 7) * 4;     // 0..28
    const int c = c0 + cl;
    const float2 st = stat[b * NGRP + c / CPG];
    const float ga = gamma[c], be = beta[c];
    const float4 v = *(const float4*)(x + ((size_t)b * CH + c) * NTOK + n0 + nl);
    tile[cl][nl + 0] = f2bf((v.x - st.x) * st.y * ga + be);
    tile[cl][nl + 1] = f2bf((v.y - st.x) * st.y * ga + be);
    tile[cl][nl + 2] = f2bf((v.z - st.x) * st.y * ga + be);
    tile[cl][nl + 3] = f2bf((v.w - st.x) * st.y * ga + be);
    __syncthreads();

    const int nw = t >> 3;          // 0..31
    const int cw = (t & 7) * 4;     // 0..28
    short4v o;
    o.x = tile[cw + 0][nw];
    o.y = tile[cw + 1][nw];
    o.z = tile[cw + 2][nw];
    o.w = tile[cw + 3][nw];
    *(short4v*)(hnT + ((size_t)b * NTOK + n0 + nw) * CH + c0 + cw) = o;
}

// ---------------------------------------------------------------------------
// fp32 -> bf16 weight cast. Grid (256, 4).
// ---------------------------------------------------------------------------
__global__ __launch_bounds__(256)
void cast_weights(const float* w0, const float* w1, const float* w2, const float* w3,
                  short* o0, short* o1, short* o2, short* o3)
{
    const float* w; short* o;
    switch (blockIdx.y) {
        case 0: w = w0; o = o0; break;
        case 1: w = w1; o = o1; break;
        case 2: w = w2; o = o2; break;
        default: w = w3; o = o3; break;
    }
    const int i = blockIdx.x * 256 + threadIdx.x;
    const float4 v = ((const float4*)w)[i];
    short4v s; s.x = f2bf(v.x); s.y = f2bf(v.y); s.z = f2bf(v.z); s.w = f2bf(v.w);
    ((short4v*)o)[i] = s;
}

// ---------------------------------------------------------------------------
// bf16 MFMA GEMM (TN): C[m][n] = scale*sum_k A[m][k]*B[n][k] (+bias)(+res)
// 256 threads = 4 waves. BK in {32,64}. SWAP_XY puts m-tile on grid x (fast
// axis) so blocks sharing A rows land on the same XCD (id%8 = m%8).
// ---------------------------------------------------------------------------
template<int BM, int BN, int BK, int WAVES_M, int OUT_BF16, int BIAS_M,
         int BIAS_N, int ADD_RES, int SWAP_XY>
__global__ __launch_bounds__(256)
void mfma_gemm(const short* __restrict__ A, const short* __restrict__ B,
               void* __restrict__ Cv, const float* __restrict__ bias,
               const float* __restrict__ res, float scale,
               int K, int lda, int ldb, int ldc,
               long sA, long sB, long sC)
{
    constexpr int WAVES_N = 4 / WAVES_M;
    constexpr int WM = BM / WAVES_M;
    constexpr int WN = BN / WAVES_N;
    constexpr int MT = WM / 16;
    constexpr int NT = WN / 16;
    constexpr int KS = BK / 32;
    constexpr int TPR = BK / 8;       // threads per row (16B per thread)
    constexpr int RPI = 256 / TPR;    // rows per staging issue

    __shared__ __align__(16) short As[BM * BK];
    __shared__ __align__(16) short Bs[BN * BK];

    const int z = blockIdx.z;
    const short* Ap = A + (size_t)z * sA;
    const short* Bp = B + (size_t)z * sB;

    const int m0 = (SWAP_XY ? blockIdx.x : blockIdx.y) * BM;
    const int n0 = (SWAP_XY ? blockIdx.y : blockIdx.x) * BN;
    const int t = threadIdx.x;
    const int w = t >> 6, lane = t & 63;
    const int wm = (w % WAVES_M) * WM;
    const int wn = (w / WAVES_M) * WN;
    const int lr = lane & 15, lq = lane >> 4;

    floatx4 acc[MT][NT];
#pragma unroll
    for (int mt = 0; mt < MT; mt++)
#pragma unroll
        for (int nt = 0; nt < NT; nt++)
            acc[mt][nt] = (floatx4){0.f, 0.f, 0.f, 0.f};

    const int rA = t / TPR;
    const int kA = (t % TPR) * 8;

    for (int k0 = 0; k0 < K; k0 += BK) {
#pragma unroll
        for (int r = 0; r < BM; r += RPI)
            load_lds16(Ap + (size_t)(m0 + r + rA) * lda + k0 + kA,
                       &As[(r + rA) * BK + kA]);
#pragma unroll
        for (int r = 0; r < BN; r += RPI)
            load_lds16(Bp + (size_t)(n0 + r + rA) * ldb + k0 + kA,
                       &Bs[(r + rA) * BK + kA]);
        __syncthreads();

        short8 af[MT][KS], bfr[NT][KS];
#pragma unroll
        for (int mt = 0; mt < MT; mt++)
#pragma unroll
            for (int ks = 0; ks < KS; ks++)
                af[mt][ks] = *(const short8*)&As[(wm + mt * 16 + lr) * BK + ks * 32 + lq * 8];
#pragma unroll
        for (int nt = 0; nt < NT; nt++)
#pragma unroll
            for (int ks = 0; ks < KS; ks++)
                bfr[nt][ks] = *(const short8*)&Bs[(wn + nt * 16 + lr) * BK + ks * 32 + lq * 8];
#pragma unroll
        for (int mt = 0; mt < MT; mt++)
#pragma unroll
            for (int nt = 0; nt < NT; nt++)
#pragma unroll
                for (int ks = 0; ks < KS; ks++)
                    acc[mt][nt] = __builtin_amdgcn_mfma_f32_16x16x32_bf16(
                        af[mt][ks], bfr[nt][ks], acc[mt][nt], 0, 0, 0);
        __syncthreads();
    }

    // Epilogue. C/D: col = lane&15, row = (lane>>4)*4 + r  [m89-verified]
    const size_t cz = (size_t)z * sC;
#pragma unroll
    for (int mt = 0; mt < MT; mt++) {
#pragma unroll
        for (int nt = 0; nt < NT; nt++) {
#pragma unroll
            for (int r = 0; r < 4; r++) {
                const int row = m0 + wm + mt * 16 + lq * 4 + r;
                const int col = n0 + wn + nt * 16 + lr;
                float v = acc[mt][nt][r] * scale;
                if (BIAS_M) v += bias[row];
                if (BIAS_N) v += bias[col];
                const size_t idx = cz + (size_t)row * ldc + col;
                if (ADD_RES) v += res[idx];
                if (OUT_BF16) ((short*)Cv)[idx] = f2bf(v);
                else          ((float*)Cv)[idx] = v;
            }
        }
    }
}

// ---------------------------------------------------------------------------
// Row softmax fp32 -> bf16 P, overlaid in place (P row pitch 8192 bf16).
// ---------------------------------------------------------------------------
__global__ __launch_bounds__(256)
void softmax_rows(float* __restrict__ S)
{
    float* row = S + (size_t)blockIdx.x * NTOK;
    const int t = threadIdx.x;
    const int lane = t & 63, wave = t >> 6;
    __shared__ float redm[4], reds[4];

    float4 v[4];
#pragma unroll
    for (int j = 0; j < 4; j++) v[j] = ((const float4*)row)[t + 256 * j];

    float m = -1e30f;
#pragma unroll
    for (int j = 0; j < 4; j++)
        m = fmaxf(m, fmaxf(fmaxf(v[j].x, v[j].y), fmaxf(v[j].z, v[j].w)));
    for (int off = 32; off >= 1; off >>= 1) m = fmaxf(m, __shfl_down(m, off));
    if (lane == 0) redm[wave] = m;
    __syncthreads();
    m = fmaxf(fmaxf(redm[0], redm[1]), fmaxf(redm[2], redm[3]));

    float sum = 0.f;
#pragma unroll
    for (int j = 0; j < 4; j++) {
        v[j].x = __expf(v[j].x - m);
        v[j].y = __expf(v[j].y - m);
        v[j].z = __expf(v[j].z - m);
        v[j].w = __expf(v[j].w - m);
        sum += v[j].x + v[j].y + v[j].z + v[j].w;
    }
    for (int off = 32; off >= 1; off >>= 1) sum += __shfl_down(sum, off);
    if (lane == 0) reds[wave] = sum;
    __syncthreads();
    const float inv = 1.f / (reds[0] + reds[1] + reds[2] + reds[3]);

#pragma unroll
    for (int j = 0; j < 4; j++) {
        short4v o;
        o.x = f2bf(v[j].x * inv);
        o.y = f2bf(v[j].y * inv);
        o.z = f2bf(v[j].z * inv);
        o.w = f2bf(v[j].w * inv);
        ((short4v*)row)[t + 256 * j] = o;
    }
}

// ---------------------------------------------------------------------------
// Launch
// ---------------------------------------------------------------------------
extern "C" void kernel_launch(void* const* d_in, const int* in_sizes, int n_in,
                              void* d_out, int out_size, void* d_ws, size_t ws_size,
                              hipStream_t stream)
{
    (void)in_sizes; (void)n_in; (void)out_size; (void)ws_size;
    const float* x      = (const float*)d_in[0];
    const float* norm_w = (const float*)d_in[1];
    const float* norm_b = (const float*)d_in[2];
    const float* q_w    = (const float*)d_in[3];
    const float* q_b    = (const float*)d_in[4];
    const float* k_w    = (const float*)d_in[5];
    const float* k_b    = (const float*)d_in[6];
    const float* v_w    = (const float*)d_in[7];
    const float* v_b    = (const float*)d_in[8];
    const float* p_w    = (const float*)d_in[9];
    const float* p_b    = (const float*)d_in[10];

    const size_t CN2 = (size_t)NTOK * CH;   // elements per batch plane

    short* hnT = (short*)d_ws;              // [B][N][C] bf16
    short* Q   = hnT + BATCH * CN2;         // [B][N][C]
    short* Kb  = Q   + BATCH * CN2;         // [B][N][C]
    short* V   = Kb  + BATCH * CN2;         // [B][C][N]
    short* O   = V   + BATCH * CN2;         // [B][N][C]
    short* wq  = O   + BATCH * CN2;
    short* wk  = wq + CH * CH;
    short* wv  = wk + CH * CH;
    short* wp  = wv + CH * CH;
    float2* stat = (float2*)(wp + CH * CH);               // 128 entries
    float* S = (float*)((char*)(stat + 128));             // [2][4096][4096] fp32

    // GroupNorm + transpose + casts
    gn_stats<<<BATCH * NGRP, 256, 0, stream>>>(x, stat);
    cast_weights<<<dim3(256, 4), 256, 0, stream>>>(q_w, k_w, v_w, p_w, wq, wk, wv, wp);
    gn_apply_t<<<dim3(NTOK / 32, CH / 32, BATCH), 256, 0, stream>>>(
        x, norm_w, norm_b, stat, hnT);

    // Q/K convs: C[token][c_out] bf16, bias per col
    mfma_gemm<128, 128, 32, 2, 1, 0, 1, 0, 0><<<dim3(CH / 128, NTOK / 128, BATCH), 256, 0, stream>>>(
        hnT, wq, Q, q_b, nullptr, 1.f, CH, CH, CH, CH, (long)CN2, 0, (long)CN2);
    mfma_gemm<128, 128, 32, 2, 1, 0, 1, 0, 0><<<dim3(CH / 128, NTOK / 128, BATCH), 256, 0, stream>>>(
        hnT, wk, Kb, k_b, nullptr, 1.f, CH, CH, CH, CH, (long)CN2, 0, (long)CN2);
    // V conv: C[c_out][token] bf16, bias per row
    mfma_gemm<128, 128, 32, 2, 1, 1, 0, 0, 0><<<dim3(NTOK / 128, CH / 128, BATCH), 256, 0, stream>>>(
        wv, hnT, V, v_b, nullptr, 1.f, CH, CH, CH, NTOK, 0, (long)CN2, (long)CN2);

    const float scale = 1.0f / sqrtf((float)CH);
    // Attention, 2 batches per chunk (S = 134 MB)
    for (int c = 0; c < BATCH / 2; c++) {
        // scores: S[z][i][j] fp32
        mfma_gemm<128, 128, 32, 2, 0, 0, 0, 0, 0><<<dim3(NTOK / 128, NTOK / 128, 2), 256, 0, stream>>>(
            Q + (size_t)2 * c * CN2, Kb + (size_t)2 * c * CN2, S, nullptr, nullptr, scale,
            CH, CH, CH, NTOK, (long)CN2, (long)CN2, (long)NTOK * NTOK);
        // softmax + bf16 pack (P pitch 8192 bf16, overlaid in S)
        softmax_rows<<<2 * NTOK, 256, 0, stream>>>(S);
        // PV: O[i][c] bf16. BM=128 BN=64 BK=64, SWAP_XY for XCD A-reuse.
        mfma_gemm<128, 64, 64, 2, 1, 0, 0, 0, 1><<<dim3(NTOK / 128, CH / 64, 2), 256, 0, stream>>>(
            (const short*)S, V + (size_t)2 * c * CN2, O + (size_t)2 * c * CN2,
            nullptr, nullptr, 1.f,
            NTOK, 2 * NTOK, NTOK, CH, (long)2 * NTOK * NTOK, (long)CN2, (long)CN2);
    }

    // proj + bias + residual -> out fp32 [b][c][n]
    mfma_gemm<128, 128, 32, 2, 0, 1, 0, 1, 0><<<dim3(NTOK / 128, CH / 128, BATCH), 256, 0, stream>>>(
        wp, O, d_out, p_b, x, 1.f, CH, CH, CH, NTOK, 0, (long)CN2, (long)CN2);
}

// Round 4
// 443.578 us; speedup vs baseline: 7.6218x; 1.1482x over previous
//
#include <hip/hip_runtime.h>
#include <math.h>

#define BATCH 4
#define CH 512
#define NTOK 4096
#define NGRP 32
#define CPG 16
#define GN_EPS 1e-6f

typedef __attribute__((ext_vector_type(8))) short short8;
typedef __attribute__((ext_vector_type(4))) short short4v;
typedef __attribute__((ext_vector_type(4))) float floatx4;

__device__ __forceinline__ short f2bf(float f) {
    unsigned u = __float_as_uint(f);
    u += 0x7fffu + ((u >> 16) & 1u);
    return (short)(u >> 16);
}
__device__ __forceinline__ float bf2f(short s) {
    return __uint_as_float(((unsigned)(unsigned short)s) << 16);
}

__device__ __forceinline__ void load_lds16(const void* g, void* l) {
    __builtin_amdgcn_global_load_lds(
        (const __attribute__((address_space(1))) void*)g,
        (__attribute__((address_space(3))) void*)l,
        16, 0, 0);
}

// ---------------------------------------------------------------------------
// GroupNorm stats, partial: grid (4 parts, 128 bg). partials[bg*4+p]=(sum,ssq)
// ---------------------------------------------------------------------------
__global__ __launch_bounds__(256)
void gn_stats_partial(const float* __restrict__ x, float2* __restrict__ partials)
{
    const int part = blockIdx.x;       // 0..3
    const int bg = blockIdx.y;         // 0..127
    const float4* xp = (const float4*)(x + (size_t)bg * CPG * NTOK) + part * 4096;
    float s = 0.f, ss = 0.f;
    for (int i = threadIdx.x; i < 4096; i += 256) {
        float4 v = xp[i];
        s  += v.x + v.y + v.z + v.w;
        ss += v.x * v.x + v.y * v.y + v.z * v.z + v.w * v.w;
    }
    __shared__ float r0[4], r1[4];
    for (int off = 32; off >= 1; off >>= 1) {
        s  += __shfl_down(s, off);
        ss += __shfl_down(ss, off);
    }
    const int lane = threadIdx.x & 63, wave = threadIdx.x >> 6;
    if (lane == 0) { r0[wave] = s; r1[wave] = ss; }
    __syncthreads();
    if (threadIdx.x == 0) {
        float2 o;
        o.x = r0[0] + r0[1] + r0[2] + r0[3];
        o.y = r1[0] + r1[1] + r1[2] + r1[3];
        partials[bg * 4 + part] = o;
    }
}

// ---------------------------------------------------------------------------
// GroupNorm apply + transpose + bf16. x[b][c][n] -> hnT[b][n][c] bf16.
// Grid (NTOK/32, CH/32, BATCH).
// ---------------------------------------------------------------------------
__global__ __launch_bounds__(256)
void gn_apply_t(const float* __restrict__ x, const float* __restrict__ gamma,
                const float* __restrict__ beta, const float2* __restrict__ partials,
                short* __restrict__ hnT)
{
    const int b = blockIdx.z;
    const int c0 = blockIdx.y * 32;
    const int n0 = blockIdx.x * 32;
    __shared__ short tile[32][33];
    const int t = threadIdx.x;

    const int cl = t >> 3;          // 0..31
    const int nl = (t & 7) * 4;     // 0..28
    const int c = c0 + cl;
    const int bg = b * NGRP + c / CPG;
    float2 p0 = partials[bg * 4 + 0], p1 = partials[bg * 4 + 1];
    float2 p2 = partials[bg * 4 + 2], p3 = partials[bg * 4 + 3];
    const float inv = 1.f / (float)(CPG * NTOK);
    const float mean = (p0.x + p1.x + p2.x + p3.x) * inv;
    const float var = (p0.y + p1.y + p2.y + p3.y) * inv - mean * mean;
    const float rstd = rsqrtf(var + GN_EPS);
    const float ga = gamma[c] * rstd, be = beta[c] - mean * ga;
    const float4 v = *(const float4*)(x + ((size_t)b * CH + c) * NTOK + n0 + nl);
    tile[cl][nl + 0] = f2bf(v.x * ga + be);
    tile[cl][nl + 1] = f2bf(v.y * ga + be);
    tile[cl][nl + 2] = f2bf(v.z * ga + be);
    tile[cl][nl + 3] = f2bf(v.w * ga + be);
    __syncthreads();

    const int nw = t >> 3;
    const int cw = (t & 7) * 4;
    short4v o;
    o.x = tile[cw + 0][nw];
    o.y = tile[cw + 1][nw];
    o.z = tile[cw + 2][nw];
    o.w = tile[cw + 3][nw];
    *(short4v*)(hnT + ((size_t)b * NTOK + n0 + nw) * CH + c0 + cw) = o;
}

// ---------------------------------------------------------------------------
// Weight casts: q,k -> wqk (concat rows), v -> wv, p -> wp. Grid (256, 4).
// ---------------------------------------------------------------------------
__global__ __launch_bounds__(256)
void cast_weights(const float* q, const float* k, const float* v, const float* p,
                  short* wqk, short* wv, short* wp)
{
    const float* w; short* o;
    switch (blockIdx.y) {
        case 0: w = q; o = wqk; break;
        case 1: w = k; o = wqk + CH * CH; break;
        case 2: w = v; o = wv; break;
        default: w = p; o = wp; break;
    }
    const int i = blockIdx.x * 256 + threadIdx.x;
    const float4 vv = ((const float4*)w)[i];
    short4v s; s.x = f2bf(vv.x); s.y = f2bf(vv.y); s.z = f2bf(vv.z); s.w = f2bf(vv.w);
    ((short4v*)o)[i] = s;
}

__global__ __launch_bounds__(256)
void concat_bias(const float* q_b, const float* k_b, float* qkb)
{
    const int i = blockIdx.x * 256 + threadIdx.x;   // grid 4 -> 1024
    qkb[i] = (i < CH) ? q_b[i] : k_b[i - CH];
}

// ---------------------------------------------------------------------------
// bf16 MFMA GEMM (TN): C[m][n] = scale*sum_k A[m][k]*B[n][k] (+bias)(+res)
// ---------------------------------------------------------------------------
template<int BM, int BN, int BK, int WAVES_M, int OUT_BF16, int BIAS_M,
         int BIAS_N, int ADD_RES, int SWAP_XY>
__global__ __launch_bounds__(256)
void mfma_gemm(const short* __restrict__ A, const short* __restrict__ B,
               void* __restrict__ Cv, const float* __restrict__ bias,
               const float* __restrict__ res, float scale,
               int K, int lda, int ldb, int ldc,
               long sA, long sB, long sC)
{
    constexpr int WAVES_N = 4 / WAVES_M;
    constexpr int WM = BM / WAVES_M;
    constexpr int WN = BN / WAVES_N;
    constexpr int MT = WM / 16;
    constexpr int NT = WN / 16;
    constexpr int KS = BK / 32;
    constexpr int TPR = BK / 8;
    constexpr int RPI = 256 / TPR;

    __shared__ __align__(16) short As[BM * BK];
    __shared__ __align__(16) short Bs[BN * BK];

    const int z = blockIdx.z;
    const short* Ap = A + (size_t)z * sA;
    const short* Bp = B + (size_t)z * sB;

    const int m0 = (SWAP_XY ? blockIdx.x : blockIdx.y) * BM;
    const int n0 = (SWAP_XY ? blockIdx.y : blockIdx.x) * BN;
    const int t = threadIdx.x;
    const int w = t >> 6, lane = t & 63;
    const int wm = (w % WAVES_M) * WM;
    const int wn = (w / WAVES_M) * WN;
    const int lr = lane & 15, lq = lane >> 4;

    floatx4 acc[MT][NT];
#pragma unroll
    for (int mt = 0; mt < MT; mt++)
#pragma unroll
        for (int nt = 0; nt < NT; nt++)
            acc[mt][nt] = (floatx4){0.f, 0.f, 0.f, 0.f};

    const int rA = t / TPR;
    const int kA = (t % TPR) * 8;

    for (int k0 = 0; k0 < K; k0 += BK) {
#pragma unroll
        for (int r = 0; r < BM; r += RPI)
            load_lds16(Ap + (size_t)(m0 + r + rA) * lda + k0 + kA,
                       &As[(r + rA) * BK + kA]);
#pragma unroll
        for (int r = 0; r < BN; r += RPI)
            load_lds16(Bp + (size_t)(n0 + r + rA) * ldb + k0 + kA,
                       &Bs[(r + rA) * BK + kA]);
        __syncthreads();

        short8 af[MT][KS], bfr[NT][KS];
#pragma unroll
        for (int mt = 0; mt < MT; mt++)
#pragma unroll
            for (int ks = 0; ks < KS; ks++)
                af[mt][ks] = *(const short8*)&As[(wm + mt * 16 + lr) * BK + ks * 32 + lq * 8];
#pragma unroll
        for (int nt = 0; nt < NT; nt++)
#pragma unroll
            for (int ks = 0; ks < KS; ks++)
                bfr[nt][ks] = *(const short8*)&Bs[(wn + nt * 16 + lr) * BK + ks * 32 + lq * 8];
#pragma unroll
        for (int mt = 0; mt < MT; mt++)
#pragma unroll
            for (int nt = 0; nt < NT; nt++)
#pragma unroll
                for (int ks = 0; ks < KS; ks++)
                    acc[mt][nt] = __builtin_amdgcn_mfma_f32_16x16x32_bf16(
                        af[mt][ks], bfr[nt][ks], acc[mt][nt], 0, 0, 0);
        __syncthreads();
    }

    // C/D: col = lane&15, row = (lane>>4)*4 + r  [m89-verified]
    const size_t cz = (size_t)z * sC;
#pragma unroll
    for (int mt = 0; mt < MT; mt++) {
#pragma unroll
        for (int nt = 0; nt < NT; nt++) {
#pragma unroll
            for (int r = 0; r < 4; r++) {
                const int row = m0 + wm + mt * 16 + lq * 4 + r;
                const int col = n0 + wn + nt * 16 + lr;
                float v = acc[mt][nt][r] * scale;
                if (BIAS_M) v += bias[row];
                if (BIAS_N) v += bias[col];
                const size_t idx = cz + (size_t)row * ldc + col;
                if (ADD_RES) v += res[idx];
                if (OUT_BF16) ((short*)Cv)[idx] = f2bf(v);
                else          ((float*)Cv)[idx] = v;
            }
        }
    }
}

// ---------------------------------------------------------------------------
// Row softmax on bf16 logits, in place. Grid = BATCH*NTOK rows.
// ---------------------------------------------------------------------------
__global__ __launch_bounds__(256)
void softmax_rows_bf16(short* __restrict__ S)
{
    short* row = S + (size_t)blockIdx.x * NTOK;
    const int t = threadIdx.x;
    const int lane = t & 63, wave = t >> 6;
    __shared__ float redm[4], reds[4];

    float v[16];
#pragma unroll
    for (int j = 0; j < 2; j++) {
        short8 s8 = ((const short8*)row)[t + 256 * j];
#pragma unroll
        for (int e = 0; e < 8; e++) v[j * 8 + e] = bf2f(s8[e]);
    }

    float m = -1e30f;
#pragma unroll
    for (int e = 0; e < 16; e++) m = fmaxf(m, v[e]);
    for (int off = 32; off >= 1; off >>= 1) m = fmaxf(m, __shfl_down(m, off));
    if (lane == 0) redm[wave] = m;
    __syncthreads();
    m = fmaxf(fmaxf(redm[0], redm[1]), fmaxf(redm[2], redm[3]));

    float sum = 0.f;
#pragma unroll
    for (int e = 0; e < 16; e++) { v[e] = __expf(v[e] - m); sum += v[e]; }
    for (int off = 32; off >= 1; off >>= 1) sum += __shfl_down(sum, off);
    if (lane == 0) reds[wave] = sum;
    __syncthreads();
    const float inv = 1.f / (reds[0] + reds[1] + reds[2] + reds[3]);

#pragma unroll
    for (int j = 0; j < 2; j++) {
        short8 o;
#pragma unroll
        for (int e = 0; e < 8; e++) o[e] = f2bf(v[j * 8 + e] * inv);
        ((short8*)row)[t + 256 * j] = o;
    }
}

// ---------------------------------------------------------------------------
// Launch
// ---------------------------------------------------------------------------
extern "C" void kernel_launch(void* const* d_in, const int* in_sizes, int n_in,
                              void* d_out, int out_size, void* d_ws, size_t ws_size,
                              hipStream_t stream)
{
    (void)in_sizes; (void)n_in; (void)out_size; (void)ws_size;
    const float* x      = (const float*)d_in[0];
    const float* norm_w = (const float*)d_in[1];
    const float* norm_b = (const float*)d_in[2];
    const float* q_w    = (const float*)d_in[3];
    const float* q_b    = (const float*)d_in[4];
    const float* k_w    = (const float*)d_in[5];
    const float* k_b    = (const float*)d_in[6];
    const float* v_w    = (const float*)d_in[7];
    const float* v_b    = (const float*)d_in[8];
    const float* p_w    = (const float*)d_in[9];
    const float* p_b    = (const float*)d_in[10];

    const size_t CN2 = (size_t)NTOK * CH;       // 2,097,152

    short* hnT = (short*)d_ws;                  // [B][N][C]
    short* QK  = hnT + (size_t)BATCH * CN2;     // [B][N][1024]  (Q | K)
    short* V   = QK  + (size_t)BATCH * NTOK * 1024;   // [B][C][N]
    short* O   = V   + (size_t)BATCH * CN2;     // [B][N][C]
    short* wqk = O   + (size_t)BATCH * CN2;     // [1024][512]
    short* wv  = wqk + (size_t)1024 * CH;
    short* wp  = wv  + (size_t)CH * CH;
    short* S   = wp  + (size_t)CH * CH;         // [B][N][N] bf16
    float* qkb = (float*)(S + (size_t)BATCH * NTOK * NTOK);   // [1024]
    float2* partials = (float2*)(qkb + 1024);                 // [512]

    // GroupNorm + casts
    gn_stats_partial<<<dim3(4, BATCH * NGRP), 256, 0, stream>>>(x, partials);
    cast_weights<<<dim3(256, 4), 256, 0, stream>>>(q_w, k_w, v_w, p_w, wqk, wv, wp);
    concat_bias<<<4, 256, 0, stream>>>(q_b, k_b, qkb);
    gn_apply_t<<<dim3(NTOK / 32, CH / 32, BATCH), 256, 0, stream>>>(
        x, norm_w, norm_b, partials, hnT);

    // Fused Q+K conv: QK[b][n][0:512]=q, [512:1024]=k. 1024 blocks.
    mfma_gemm<128, 128, 64, 2, 1, 0, 1, 0, 0><<<dim3(1024 / 128, NTOK / 128, BATCH), 256, 0, stream>>>(
        hnT, wqk, QK, qkb, nullptr, 1.f, CH, CH, CH, 1024,
        (long)CN2, 0, (long)NTOK * 1024);
    // V conv: V[b][c][n]
    mfma_gemm<128, 128, 64, 2, 1, 1, 0, 0, 0><<<dim3(NTOK / 128, CH / 128, BATCH), 256, 0, stream>>>(
        wv, hnT, V, v_b, nullptr, 1.f, CH, CH, CH, NTOK,
        0, (long)CN2, (long)CN2);

    const float scale = 1.0f / sqrtf((float)CH);
    // scores: S[b][i][j] bf16, all batches (4096 blocks)
    mfma_gemm<128, 128, 64, 2, 1, 0, 0, 0, 0><<<dim3(NTOK / 128, NTOK / 128, BATCH), 256, 0, stream>>>(
        QK, QK + CH, S, nullptr, nullptr, scale, CH, 1024, 1024, NTOK,
        (long)NTOK * 1024, (long)NTOK * 1024, (long)NTOK * NTOK);
    // softmax in place on bf16
    softmax_rows_bf16<<<BATCH * NTOK, 256, 0, stream>>>(S);
    // PV: O[b][i][c] bf16. 1024 blocks (4/CU), SWAP_XY for A-reuse.
    mfma_gemm<128, 64, 64, 2, 1, 0, 0, 0, 1><<<dim3(NTOK / 128, CH / 64, BATCH), 256, 0, stream>>>(
        S, V, O, nullptr, nullptr, 1.f, NTOK, NTOK, NTOK, CH,
        (long)NTOK * NTOK, (long)CN2, (long)CN2);

    // proj + bias + residual -> out fp32 [b][c][n]
    mfma_gemm<128, 128, 64, 2, 0, 1, 0, 1, 0><<<dim3(NTOK / 128, CH / 128, BATCH), 256, 0, stream>>>(
        wp, O, d_out, p_b, x, 1.f, CH, CH, CH, NTOK,
        0, (long)CN2, (long)CN2);
}